// Round 7
// baseline (238.236 us; speedup 1.0000x reference)
//
#include <hip/hip_runtime.h>
#include <math.h>

// Problem constants (fixed by the reference)
#define B_  8
#define C_  256
#define N_  4096        // H*W
#define NJC (N_ / 128)  // 32 j-iterations of 128

using frag  = __attribute__((ext_vector_type(8))) short;   // 8 bf16 = 16 B
using f32x4 = __attribute__((ext_vector_type(4))) float;

__device__ __forceinline__ unsigned short f2bf(float f) {   // RNE fp32 -> bf16
    unsigned u = __float_as_uint(f);
    u += 0x7fffu + ((u >> 16) & 1u);
    return (unsigned short)(u >> 16);
}
__device__ __forceinline__ float bf2f(unsigned short h) {
    return __uint_as_float(((unsigned)h) << 16);
}
#define PK2(a, b) (((unsigned)(a)) | (((unsigned)(b)) << 16))

__device__ __forceinline__ f32x4 fmax4(f32x4 a, f32x4 b) {
    f32x4 r;
    r[0] = fmaxf(a[0], b[0]); r[1] = fmaxf(a[1], b[1]);
    r[2] = fmaxf(a[2], b[2]); r[3] = fmaxf(a[3], b[3]);
    return r;
}

// ---------------------------------------------------------------------------
// Kernel 0: weight prep -> frag-ordered bf16 weights in ws.
//   whf: 20 groups x 8 kc x 64 lanes x 8 bf16  (g 0,1=q; 2,3=k; 4..19=v)
//   wlf: 4 groups (q,k lo part), same shape.
// Fragment (g,kc,lane=(quad,l16)) holds W[g*16+l16][kc*32+quad*8 .. +8].
// Works as A-operand (m=W-row) or B-operand (n=W-row) -- same lane map.
// ---------------------------------------------------------------------------
__global__ __launch_bounds__(256) void wprep_kernel(
    const float* __restrict__ wq, const float* __restrict__ wk,
    const float* __restrict__ wv,
    unsigned short* __restrict__ whf, unsigned short* __restrict__ wlf)
{
    const int fid  = blockIdx.x * 256 + threadIdx.x;   // 0..10239
    if (fid >= 20 * 8 * 64) return;
    const int g    = fid >> 9;
    const int kc   = (fid >> 6) & 7;
    const int lane = fid & 63;
    const int r16  = lane & 15, q = lane >> 4;

    const float* src; int row;
    if (g < 2)      { src = wq; row = g * 16 + r16; }
    else if (g < 4) { src = wk; row = (g - 2) * 16 + r16; }
    else            { src = wv; row = (g - 4) * 16 + r16; }

    const float* wp = src + row * 256 + kc * 32 + q * 8;
    float v[8];
#pragma unroll
    for (int j = 0; j < 8; ++j) v[j] = wp[j];

    unsigned short h[8];
#pragma unroll
    for (int j = 0; j < 8; ++j) h[j] = f2bf(v[j]);
    uint4 U;
    U.x = PK2(h[0], h[1]); U.y = PK2(h[2], h[3]);
    U.z = PK2(h[4], h[5]); U.w = PK2(h[6], h[7]);
    *(uint4*)&whf[(size_t)fid * 8] = U;

    if (g < 4) {
        unsigned short l[8];
#pragma unroll
        for (int j = 0; j < 8; ++j) l[j] = f2bf(v[j] - bf2f(h[j]));
        uint4 V;
        V.x = PK2(l[0], l[1]); V.y = PK2(l[2], l[3]);
        V.z = PK2(l[4], l[5]); V.w = PK2(l[6], l[7]);
        *(uint4*)&wlf[(size_t)fid * 8] = V;
    }
}

// ---------------------------------------------------------------------------
// Kernel 1: MFMA qkv projection — NO LDS; x kept in VGPRs (read once).
// grid (N/64, B), 256 threads (4 waves). Wave w owns pixels n0+w*16+l16.
//   q/k: mfma(W, X) -> D[m=out-ch][n=pixel]  (pixel-major stores to [n][32])
//   v:   mfma(X, W) -> D[m=pixel][n=ch]      (4 consecutive pixels/lane ->
//        uint2 stores to [c][n], 4x wider than scalar)
// ---------------------------------------------------------------------------
__global__ __launch_bounds__(256, 2) void proj_kernel(
    const float* __restrict__ x,
    const float* __restrict__ bq, const float* __restrict__ bk,
    const float* __restrict__ bv,
    const unsigned short* __restrict__ whf, const unsigned short* __restrict__ wlf,
    unsigned short* __restrict__ qh, unsigned short* __restrict__ ql,
    unsigned short* __restrict__ kh, unsigned short* __restrict__ kl,
    unsigned short* __restrict__ vbf)
{
    const int tid  = threadIdx.x;
    const int w    = tid >> 6;
    const int lane = tid & 63;
    const int quad = lane >> 4;
    const int l16  = lane & 15;
    const int n0   = blockIdx.x * 64;
    const int b    = blockIdx.y;
    const int n    = n0 + w * 16 + l16;

    // ---- load all 64 x values for this lane's frag role:
    //      x[c][n] for c = kc*32 + quad*8 + j ----
    float xr[64];
    {
        const float* xp = x + (size_t)b * C_ * N_ + (size_t)(quad * 8) * N_ + n;
#pragma unroll
        for (int kc = 0; kc < 8; ++kc)
#pragma unroll
            for (int j = 0; j < 8; ++j)
                xr[kc * 8 + j] = xp[(size_t)(kc * 32 + j) * N_];
    }

    const frag* wh = (const frag*)whf;
    const frag* wl = (const frag*)wlf;

    f32x4 acc[20];
#pragma unroll
    for (int g = 0; g < 20; ++g) acc[g] = (f32x4){0.f, 0.f, 0.f, 0.f};

#pragma unroll
    for (int kc = 0; kc < 8; ++kc) {
        frag bh, bl;
#pragma unroll
        for (int j = 0; j < 8; ++j) {
            const float v = xr[kc * 8 + j];
            const unsigned short hb = f2bf(v);
            bh[j] = (short)hb;
            bl[j] = (short)f2bf(v - bf2f(hb));
        }

        // q/k: A = W (hi/lo), B = X (hi/lo), 3-term split
#pragma unroll
        for (int g = 0; g < 4; ++g) {
            const frag ah = wh[(g * 8 + kc) * 64 + lane];
            const frag al = wl[(g * 8 + kc) * 64 + lane];
            acc[g] = __builtin_amdgcn_mfma_f32_16x16x32_bf16(ah, bh, acc[g], 0, 0, 0);
            acc[g] = __builtin_amdgcn_mfma_f32_16x16x32_bf16(al, bh, acc[g], 0, 0, 0);
            acc[g] = __builtin_amdgcn_mfma_f32_16x16x32_bf16(ah, bl, acc[g], 0, 0, 0);
        }
        // v: A = X, B = W  ->  D[m=pixel][n=c]
#pragma unroll
        for (int g = 4; g < 20; ++g) {
            const frag ah = wh[(g * 8 + kc) * 64 + lane];
            acc[g] = __builtin_amdgcn_mfma_f32_16x16x32_bf16(bh, ah, acc[g], 0, 0, 0);
        }
    }

    // ---- q/k epilogue: lane col = l16 = pixel, rows = out-ch quad*4+r ----
#pragma unroll
    for (int g = 0; g < 4; ++g) {
        const bool isq = (g < 2);
        const float* bias = isq ? bq : bk;
        const int dbase = (isq ? g : g - 2) * 16 + quad * 4;
        unsigned short hs[4], ls[4];
#pragma unroll
        for (int r = 0; r < 4; ++r) {
            const float f = acc[g][r] + bias[dbase + r];
            hs[r] = f2bf(f);
            ls[r] = f2bf(f - bf2f(hs[r]));
        }
        const size_t off = ((size_t)(b * N_ + n)) * 32 + dbase;
        *(uint2*)&(isq ? qh : kh)[off] = make_uint2(PK2(hs[0], hs[1]), PK2(hs[2], hs[3]));
        *(uint2*)&(isq ? ql : kl)[off] = make_uint2(PK2(ls[0], ls[1]), PK2(ls[2], ls[3]));
    }

    // ---- v epilogue: lane col = l16 = c-in-tile, rows = pixel quad*4+r ----
#pragma unroll
    for (int g = 4; g < 20; ++g) {
        const int c = (g - 4) * 16 + l16;
        const float bb = bv[c];
        unsigned short vs[4];
#pragma unroll
        for (int r = 0; r < 4; ++r) vs[r] = f2bf(acc[g][r] + bb);
        const size_t off = ((size_t)b * C_ + c) * N_ + n0 + w * 16 + quad * 4;
        *(uint2*)&vbf[off] = make_uint2(PK2(vs[0], vs[1]), PK2(vs[2], vs[3]));
    }
}

// ---------------------------------------------------------------------------
// Kernel 2: MFMA flash attention v3 — frag-ordered LDS (conflict-free b128).
// Block = 512 threads (8 waves), i-tile = 128 rows. grid (N/128, B) = 1/CU.
// kbuf frag f = js*64 + quad*16 + l16 (16 B each): reads lane-linear.
// p_s  frag F = ((it*4+ks)*4+quad), addr = F*128 + l16*8 (shorts): reads
//   lane-linear; writes are 4-way (8 uint2/wave, negligible).
// Single barrier/iter; K double-buffered via regs (load during softmax).
// ---------------------------------------------------------------------------
__global__ __launch_bounds__(512, 2) void attn_kernel(
    const unsigned short* __restrict__ qh, const unsigned short* __restrict__ ql,
    const unsigned short* __restrict__ khg, const unsigned short* __restrict__ klg,
    const unsigned short* __restrict__ vbf,
    const float* __restrict__ x, const float* __restrict__ alpha_p,
    float* __restrict__ out)
{
    __shared__ __align__(16) short kbuf[2][2][4096];   // 32 KB (frag-ordered)
    __shared__ __align__(16) short p_s[2][16384];      // 64 KB (frag-ordered)
    __shared__ float alpha_s[2][128];
    __shared__ float l_s[128];

    const int tid  = threadIdx.x;
    const int w    = tid >> 6;        // wave 0..7
    const int lane = tid & 63;
    const int quad = lane >> 4;
    const int l16  = lane & 15;
    const int b    = blockIdx.y;
    const int i0   = blockIdx.x * 128;

    // K staging role for this thread: frag f = tid -> (js=tid>>6, l16=tid&15,
    // quad=(tid>>4)&3); global load is permuted-but-contiguous (full coalesce)
    const int knb = (tid >> 6) * 16 + (tid & 15);       // n offset in chunk
    const int kdg = ((tid >> 4) & 3) * 8;               // d offset

    // Q B-frags (constant): lane holds q[i = i0+16w+l16][d = 8*quad..+8]
    const size_t qoff = ((size_t)(b * N_ + i0 + w * 16 + l16)) * 32 + quad * 8;
    const frag qhf = *(const frag*)(qh + qoff);
    const frag qlf = *(const frag*)(ql + qoff);

    const unsigned short* khb = khg + (size_t)b * N_ * 32;
    const unsigned short* klb = klg + (size_t)b * N_ * 32;
    const unsigned short* vb  = vbf + (size_t)b * C_ * N_;

    f32x4 o[8][2];   // [i-subtile][c-subtile], c = w*32 + ct*16 + l16
#pragma unroll
    for (int it = 0; it < 8; ++it) {
        o[it][0] = (f32x4){0.f, 0.f, 0.f, 0.f};
        o[it][1] = (f32x4){0.f, 0.f, 0.f, 0.f};
    }

    float m_run = -INFINITY, l_run = 0.f;

    // ---- prologue: stage K(0) into kbuf[0] ----
    {
        const uint4 h0 = *(const uint4*)(khb + (size_t)knb * 32 + kdg);
        const uint4 l0 = *(const uint4*)(klb + (size_t)knb * 32 + kdg);
        *(uint4*)&kbuf[0][0][tid * 8] = h0;
        *(uint4*)&kbuf[0][1][tid * 8] = l0;
    }
    __syncthreads();

    for (int jc = 0; jc < NJC; ++jc) {
        const int bf = jc & 1;

        // ---- S^T from kbuf[bf]: frag reads lane-linear (conflict-free) ----
        f32x4 st[8];
#pragma unroll
        for (int js = 0; js < 8; ++js) {
            const frag ka  = *(const frag*)&kbuf[bf][0][(js * 64 + lane) * 8];
            const frag kb2 = *(const frag*)&kbuf[bf][1][(js * 64 + lane) * 8];
            f32x4 s = (f32x4){0.f, 0.f, 0.f, 0.f};
            s = __builtin_amdgcn_mfma_f32_16x16x32_bf16(ka, qhf, s, 0, 0, 0);
            s = __builtin_amdgcn_mfma_f32_16x16x32_bf16(ka, qlf, s, 0, 0, 0);
            s = __builtin_amdgcn_mfma_f32_16x16x32_bf16(kb2, qhf, s, 0, 0, 0);
            st[js] = s;
        }

        // ---- issue K(jc+1) global->regs (latency hidden by softmax) ----
        const int jn = (jc + 1 < NJC) ? jc + 1 : jc;
        const uint4 knh = *(const uint4*)(khb + (size_t)(jn * 128 + knb) * 32 + kdg);
        const uint4 knl = *(const uint4*)(klb + (size_t)(jn * 128 + knb) * 32 + kdg);

        // ---- online softmax, rows i = w*16 + l16 ----
        f32x4 t0 = fmax4(fmax4(st[0], st[1]), fmax4(st[2], st[3]));
        f32x4 t1 = fmax4(fmax4(st[4], st[5]), fmax4(st[6], st[7]));
        t0 = fmax4(t0, t1);
        float mx = fmaxf(fmaxf(t0[0], t0[1]), fmaxf(t0[2], t0[3]));
        mx = fmaxf(mx, __shfl_xor(mx, 16));
        mx = fmaxf(mx, __shfl_xor(mx, 32));
        const float mnew = fmaxf(m_run, mx);
        const float sc   = __expf(m_run - mnew);

        f32x4 ps4 = (f32x4){0.f, 0.f, 0.f, 0.f};
#pragma unroll
        for (int js = 0; js < 8; ++js) {
#pragma unroll
            for (int r = 0; r < 4; ++r) st[js][r] = __expf(st[js][r] - mnew);
            ps4[0] += st[js][0]; ps4[1] += st[js][1];
            ps4[2] += st[js][2]; ps4[3] += st[js][3];
        }
        float ps = (ps4[0] + ps4[1]) + (ps4[2] + ps4[3]);
        ps += __shfl_xor(ps, 16);
        ps += __shfl_xor(ps, 32);
        l_run = l_run * sc + ps;
        m_run = mnew;
        if (quad == 0) alpha_s[bf][w * 16 + l16] = sc;

        // ---- P -> bf16 -> p_s[bf] (frag-ordered A-layout) ----
        // value (i=w*16+l16, j=js*16+quad*4+r) -> frag F = (w*4+(js>>1))*4
        //   + (js&1)*2 + (quad>>1), offset l16*8 + (quad&1)*4
#pragma unroll
        for (int js = 0; js < 8; ++js) {
            const unsigned a0 = __float_as_uint(st[js][0]) + 0x8000u;
            const unsigned a1 = __float_as_uint(st[js][1]) + 0x8000u;
            const unsigned a2 = __float_as_uint(st[js][2]) + 0x8000u;
            const unsigned a3 = __float_as_uint(st[js][3]) + 0x8000u;
            const unsigned p01 = __builtin_amdgcn_perm(a1, a0, 0x07060302u);
            const unsigned p23 = __builtin_amdgcn_perm(a3, a2, 0x07060302u);
            const int F = (w * 4 + (js >> 1)) * 4 + (js & 1) * 2 + (quad >> 1);
            *(uint2*)&p_s[bf][F * 128 + l16 * 8 + (quad & 1) * 4] =
                make_uint2(p01, p23);
        }

        // ---- stage K(jc+1) into kbuf[bf^1] (lane-linear write) ----
        *(uint4*)&kbuf[bf ^ 1][0][tid * 8] = knh;
        *(uint4*)&kbuf[bf ^ 1][1][tid * 8] = knl;

        __syncthreads();   // single barrier per iteration

        // ---- V loads for this chunk: c = w*32 + ct*16 + l16 ----
        frag vf[4][2];
#pragma unroll
        for (int ks = 0; ks < 4; ++ks)
#pragma unroll
            for (int ct = 0; ct < 2; ++ct)
                vf[ks][ct] = *(const frag*)(vb
                    + (size_t)(w * 32 + ct * 16 + l16) * N_
                    + jc * 128 + ks * 32 + quad * 8);

        // ---- rescale O ----
#pragma unroll
        for (int it = 0; it < 8; ++it)
#pragma unroll
            for (int r = 0; r < 4; ++r) {
                const float al = alpha_s[bf][it * 16 + quad * 4 + r];
                o[it][0][r] *= al;
                o[it][1][r] *= al;
            }

        // ---- PV: A = P (LDS frag reads, lane-linear), B = V regs ----
#pragma unroll
        for (int ks = 0; ks < 4; ++ks) {
#pragma unroll
            for (int it = 0; it < 8; ++it) {
                const int F = (it * 4 + ks) * 4 + quad;
                const frag pf = *(const frag*)&p_s[bf][F * 128 + l16 * 8];
                o[it][0] = __builtin_amdgcn_mfma_f32_16x16x32_bf16(pf, vf[ks][0], o[it][0], 0, 0, 0);
                o[it][1] = __builtin_amdgcn_mfma_f32_16x16x32_bf16(pf, vf[ks][1], o[it][1], 0, 0, 0);
            }
        }
    }

    // ---- epilogue: out = alpha * O / l + x ----
    if (quad == 0) l_s[w * 16 + l16] = l_run;
    __syncthreads();
    const float av = alpha_p[0];

#pragma unroll
    for (int it = 0; it < 8; ++it) {
        float invl[4];
#pragma unroll
        for (int r = 0; r < 4; ++r) invl[r] = 1.f / l_s[it * 16 + quad * 4 + r];
#pragma unroll
        for (int ct = 0; ct < 2; ++ct) {
            const int c = w * 32 + ct * 16 + l16;
            const size_t base = (size_t)b * C_ * N_ + (size_t)c * N_
                                + i0 + it * 16 + quad * 4;
            const float4 xv = *(const float4*)(x + base);
            float4 ov;
            ov.x = av * (o[it][ct][0] * invl[0]) + xv.x;
            ov.y = av * (o[it][ct][1] * invl[1]) + xv.y;
            ov.z = av * (o[it][ct][2] * invl[2]) + xv.z;
            ov.w = av * (o[it][ct][3] * invl[3]) + xv.w;
            *(float4*)(out + base) = ov;
        }
    }
}

// ---------------------------------------------------------------------------
extern "C" void kernel_launch(void* const* d_in, const int* in_sizes, int n_in,
                              void* d_out, int out_size, void* d_ws, size_t ws_size,
                              hipStream_t stream)
{
    const float* x  = (const float*)d_in[0];
    const float* wq = (const float*)d_in[1];
    const float* bq = (const float*)d_in[2];
    const float* wk = (const float*)d_in[3];
    const float* bk = (const float*)d_in[4];
    const float* wv = (const float*)d_in[5];
    const float* bv = (const float*)d_in[6];
    const float* al = (const float*)d_in[7];
    float* out = (float*)d_out;

    // workspace: qh,ql,kh,kl 2MB each; vbf 16MB; whf 160KB; wlf 32KB
    char* ws = (char*)d_ws;
    unsigned short* qh  = (unsigned short*)(ws + 0);
    unsigned short* ql  = (unsigned short*)(ws + (size_t)2  * 1024 * 1024);
    unsigned short* kh  = (unsigned short*)(ws + (size_t)4  * 1024 * 1024);
    unsigned short* kl  = (unsigned short*)(ws + (size_t)6  * 1024 * 1024);
    unsigned short* vbf = (unsigned short*)(ws + (size_t)8  * 1024 * 1024);
    unsigned short* whf = (unsigned short*)(ws + (size_t)24 * 1024 * 1024);
    unsigned short* wlf = (unsigned short*)(ws + (size_t)24 * 1024 * 1024 + 256 * 1024);

    wprep_kernel<<<40, 256, 0, stream>>>(wq, wk, wv, whf, wlf);
    proj_kernel<<<dim3(N_ / 64, B_), 256, 0, stream>>>(
        x, bq, bk, bv, whf, wlf, qh, ql, kh, kl, vbf);
    attn_kernel<<<dim3(N_ / 128, B_), 512, 0, stream>>>(
        qh, ql, kh, kl, vbf, x, al, out);
}